// Round 9
// baseline (111.030 us; speedup 1.0000x reference)
//
#include <hip/hip_runtime.h>
#include <hip/hip_bf16.h>

typedef __bf16 bf16x8 __attribute__((ext_vector_type(8)));
typedef float  f32x4  __attribute__((ext_vector_type(4)));
typedef float  f32x16 __attribute__((ext_vector_type(16)));
typedef unsigned int u32x4 __attribute__((ext_vector_type(4)));

// ---------------------------------------------------------------------------
// prep: 768 blocks x 256 thr, one launch.
//   b <  256: pack Atp[kb][n][j] = bf16(A[kb*8+j][n])   (k-major 8-elem tiles
//             so a 32x32x16 MFMA B-frag load = 512B contiguous per 32 lanes)
//   b >= 256: Bt[4096][128] = bf16(B[128][4096])^T       (32x32 LDS tiles)
// ---------------------------------------------------------------------------
__global__ void prep(const float* __restrict__ A, __bf16* __restrict__ Atp,
                     const float* __restrict__ B, __bf16* __restrict__ Bt) {
    const int t = threadIdx.x;
    int b = blockIdx.x;
    if (b < 256) {
        __shared__ float tf[64][36];
        const int kbase = (b >> 2) * 64;
        const int nbase = (b & 3) * 32;
        const int r = t >> 2, c0 = (t & 3) * 8;
        const float* src = &A[(size_t)(kbase + r) * 128 + nbase + c0];
        *reinterpret_cast<f32x4*>(&tf[r][c0])     = *reinterpret_cast<const f32x4*>(src);
        *reinterpret_cast<f32x4*>(&tf[r][c0 + 4]) = *reinterpret_cast<const f32x4*>(src + 4);
        __syncthreads();
        const int kb = t >> 5, n = t & 31;
        bf16x8 o;
#pragma unroll
        for (int j = 0; j < 8; ++j) o[j] = (__bf16)tf[kb * 8 + j][n];
        *reinterpret_cast<bf16x8*>(
            &Atp[((size_t)((kbase >> 3) + kb) * 128 + nbase + n) * 8]) = o;
    } else {
        __shared__ float tile[32][33];
        b -= 256;
        const int bc = (b & 127) * 32;   // col base in B
        const int br = (b >> 7) * 32;    // row base in B
        const int tx = t & 31, ty = t >> 5;
#pragma unroll
        for (int p = 0; p < 4; ++p)
            tile[ty + p * 8][tx] = B[(size_t)(br + ty + p * 8) * 4096 + bc + tx];
        __syncthreads();
#pragma unroll
        for (int p = 0; p < 4; ++p)
            Bt[(size_t)(bc + ty + p * 8) * 128 + br + tx] = (__bf16)tile[tx][ty + p * 8];
    }
}

// ---------------------------------------------------------------------------
// GEMM1 (barrier-free streaming): Up[z][8192][128] partial over K.
// grid (256, KSG) x 512 thr: 4 N-waves x 2 K-half waves per block; total
// K-split = 2*KSG. MFMA operands read DIRECTLY from global:
//   A-frag: inp f32, 64B/row segments (rows l&31, lane pairs cover 64B), cvt
//           to bf16 in regs.  Each inp element read by exactly ONE block.
//   B-frag: packed Atp (L2-resident 1 MB), 512B contiguous per 32 lanes.
// No LDS staging, no barriers in the K loop; 4 blocks/CU = 32 waves/CU hide
// latency via TLP. One end-of-kernel LDS exchange combines the 2 K-halves.
// ---------------------------------------------------------------------------
__global__ __launch_bounds__(512, 8) void gemm1e(const float* __restrict__ inp,
                                                 const __bf16* __restrict__ Atp,
                                                 __bf16* __restrict__ Uout,
                                                 int nsteps) {
    __shared__ float sX[4][32][32];     // 16 KB K-half exchange
    const int t    = threadIdx.x;
    const int lane = t & 63;
    const int wid  = t >> 6;
    const int nw   = wid & 3;           // N-wave: cols wn..wn+31
    const int kh   = wid >> 2;          // K-half 0/1
    const int wn   = nw << 5;
    const int fm   = lane & 31;
    const int fhk  = (lane >> 5) << 3;  // 0 / 8
    const int brow = blockIdx.x * 32;
    const int k0   = (blockIdx.y * 2 + kh) * nsteps * 16;

    const float*  ap = inp + (size_t)(brow + fm) * 4096 + k0 + fhk;
    const __bf16* bp = Atp + ((size_t)((k0 >> 3) + (lane >> 5)) * 128 + wn + fm) * 8;

    f32x16 acc = {};
#pragma unroll 2
    for (int s = 0; s < nsteps; ++s) {
        f32x4 a0 = *reinterpret_cast<const f32x4*>(ap);
        f32x4 a1 = *reinterpret_cast<const f32x4*>(ap + 4);
        bf16x8 bf = *reinterpret_cast<const bf16x8*>(bp);
        bf16x8 af;
        af[0] = (__bf16)a0[0]; af[1] = (__bf16)a0[1];
        af[2] = (__bf16)a0[2]; af[3] = (__bf16)a0[3];
        af[4] = (__bf16)a1[0]; af[5] = (__bf16)a1[1];
        af[6] = (__bf16)a1[2]; af[7] = (__bf16)a1[3];
        acc = __builtin_amdgcn_mfma_f32_32x32x16_bf16(af, bf, acc, 0, 0, 0);
        ap += 16;        // K advances 16
        bp += 2048;      // 2 k-blocks x 128 n x 8
    }

    // combine the two K-halves via LDS, then store bf16 partial.
    const int rb = (lane >> 5) << 2;
    if (kh) {
#pragma unroll
        for (int reg = 0; reg < 16; ++reg) {
            const int r = (reg & 3) + ((reg >> 2) << 3) + rb;
            sX[nw][r][fm] = acc[reg];
        }
    }
    __syncthreads();
    if (!kh) {
        __bf16* Up = Uout + (size_t)blockIdx.y * 8192 * 128;
#pragma unroll
        for (int reg = 0; reg < 16; ++reg) {
            const int r = (reg & 3) + ((reg >> 2) << 3) + rb;
            Up[(size_t)(brow + r) * 128 + wn + fm] = (__bf16)(acc[reg] + sX[nw][r][fm]);
        }
    }
}

// ---------------------------------------------------------------------------
// Reduce grid-ksplit partials: U = bf16(sum_j Up[j]).  1M elems.
// ---------------------------------------------------------------------------
__global__ void reduceU(const __bf16* __restrict__ Up, __bf16* __restrict__ U,
                        int ksplit) {
    const size_t i = ((size_t)blockIdx.x * 256 + threadIdx.x) * 8;
    float s[8] = {};
    for (int j = 0; j < ksplit; ++j) {
        bf16x8 a = *reinterpret_cast<const bf16x8*>(Up + (size_t)j * 8192 * 128 + i);
#pragma unroll
        for (int e = 0; e < 8; ++e) s[e] += (float)a[e];
    }
    bf16x8 r;
#pragma unroll
    for (int e = 0; e < 8; ++e) r[e] = (__bf16)s[e];
    *reinterpret_cast<bf16x8*>(U + i) = r;
}

// ---------------------------------------------------------------------------
// GEMM2: out[8192][4096](f32) = U[8192][128](bf16) @ B (as Bt[4096][128] bf16)
// K=128 fully staged. BM=64 x BN=128. 4096 blocks x 256 thr (4 waves 2x2).
// Operand-swapped MFMA -> transposed C/D -> dwordx4 stores.
// Bijective XCD chunk swizzle (4096 = 8 x 512).   (proven R6/R8)
// ---------------------------------------------------------------------------
__global__ __launch_bounds__(256, 1) void gemm2(const __bf16* __restrict__ U,
                                                const __bf16* __restrict__ Bt,
                                                float* __restrict__ out) {
    __shared__ __align__(16) __bf16 sU[64][128];    // 16 KB
    __shared__ __align__(16) __bf16 sB[128][128];   // 32 KB
    const int t    = threadIdx.x;
    const int lane = t & 63;
    const int wid  = t >> 6;
    const int bx0  = blockIdx.x;
    const int bx   = (bx0 & 7) * 512 + (bx0 >> 3);  // XCD-contiguous chunks
    const int brow = (bx >> 5) * 64;    // 128 row tiles
    const int bcol = (bx & 31) * 128;   // 32 col tiles

    // stage U tile (64 rows x 128 k)
#pragma unroll
    for (int p = 0; p < 4; ++p) {
        const int c = t + p * 256;
        const int row = c >> 4, col = (c & 15) << 3;
        u32x4 v = *reinterpret_cast<const u32x4*>(&U[(size_t)(brow + row) * 128 + col]);
        *reinterpret_cast<u32x4*>(&sU[row][col ^ ((row & 7) << 3)]) = v;
    }
    // stage Bt tile (128 n-rows x 128 k)
#pragma unroll
    for (int p = 0; p < 8; ++p) {
        const int c = t + p * 256;
        const int row = c >> 4, col = (c & 15) << 3;
        u32x4 v = *reinterpret_cast<const u32x4*>(&Bt[(size_t)(bcol + row) * 128 + col]);
        *reinterpret_cast<u32x4*>(&sB[row][col ^ ((row & 7) << 3)]) = v;
    }
    __syncthreads();

    const int wm = (wid >> 1) << 5;   // 0 / 32
    const int wn = (wid & 1) << 6;    // 0 / 64
    const int fr = lane & 15;
    const int fk = (lane >> 4) << 3;

    // acc_s[nf][mf]: swapped-operand accumulators (transposed C/D)
    f32x4 acc_s[4][2] = {};
#pragma unroll
    for (int ks = 0; ks < 4; ++ks) {
        const int k = ks * 32 + fk;
        bf16x8 af[2];
#pragma unroll
        for (int am = 0; am < 2; ++am) {
            const int r = wm + am * 16 + fr;
            af[am] = *reinterpret_cast<const bf16x8*>(&sU[r][k ^ ((r & 7) << 3)]);
        }
#pragma unroll
        for (int bn = 0; bn < 4; ++bn) {
            const int r = wn + bn * 16 + fr;
            bf16x8 bfv = *reinterpret_cast<const bf16x8*>(&sB[r][k ^ ((r & 7) << 3)]);
#pragma unroll
            for (int am = 0; am < 2; ++am)
                acc_s[bn][am] = __builtin_amdgcn_mfma_f32_16x16x32_bf16(
                    bfv, af[am], acc_s[bn][am], 0, 0, 0);
        }
    }

    // epilogue (swapped layout): f32x4 per (bn,am) -> dwordx4 stores
    const int g4 = (lane >> 4) << 2;
#pragma unroll
    for (int am = 0; am < 2; ++am) {
        const int orow = brow + wm + am * 16 + fr;
#pragma unroll
        for (int bn = 0; bn < 4; ++bn) {
            const int ocol = bcol + wn + bn * 16 + g4;
            *reinterpret_cast<f32x4*>(&out[(size_t)orow * 4096 + ocol]) = acc_s[bn][am];
        }
    }
}

// ---------------------------------------------------------------------------
extern "C" void kernel_launch(void* const* d_in, const int* in_sizes, int n_in,
                              void* d_out, int out_size, void* d_ws, size_t ws_size,
                              hipStream_t stream) {
    const float* inp = (const float*)d_in[0];   // [8192,4096]
    const float* A   = (const float*)d_in[1];   // [4096,128]
    const float* B   = (const float*)d_in[2];   // [128,4096]
    float* out = (float*)d_out;                 // [8192,4096]

    char* ws = (char*)d_ws;
    __bf16* Atp = (__bf16*)(ws);                      // [512][128][8]      1 MB
    __bf16* Bt  = (__bf16*)(ws + (1 << 20));          // [4096][128]        1 MB
    __bf16* U   = (__bf16*)(ws + (2 << 20));          // [8192][128]        2 MB
    __bf16* Up  = (__bf16*)(ws + (4 << 20));          // [ksg][8192][128]

    prep<<<768, 256, 0, stream>>>(A, Atp, B, Bt);

    // grid-ksplit KSG (total K-split = 2*KSG via intra-block K-half waves)
    const int ksg = (ws_size >= (size_t)(12 << 20)) ? 4
                  : (ws_size >= (size_t)(8 << 20)) ? 2 : 1;
    if (ksg > 1) {
        gemm1e<<<dim3(256, ksg), 512, 0, stream>>>(inp, Atp, Up, 128 / ksg);
        reduceU<<<512, 256, 0, stream>>>(Up, U, ksg);
    } else {
        gemm1e<<<dim3(256, 1), 512, 0, stream>>>(inp, Atp, U, 128);
    }

    gemm2<<<4096, 256, 0, stream>>>(U, Bt, out);
}

// Round 10
// 74.124 us; speedup vs baseline: 1.4979x; 1.4979x over previous
//
#include <hip/hip_runtime.h>
#include <hip/hip_bf16.h>
#include <hip/hip_cooperative_groups.h>

namespace cg = cooperative_groups;

typedef __bf16 bf16x8 __attribute__((ext_vector_type(8)));
typedef __bf16 bf16x4 __attribute__((ext_vector_type(4)));
typedef float  f32x4  __attribute__((ext_vector_type(4)));
typedef unsigned int u32x4 __attribute__((ext_vector_type(4)));

// ===========================================================================
// Cooperative fused kernel: prep -> gemm1(ksplit2) -> (reduce+gemm2).
// 512 blocks x 512 thr, 48 KB LDS union, 2 blocks/CU co-resident.
// ===========================================================================
__global__ __launch_bounds__(512, 4) void fused_all(
        const float* __restrict__ inp,   // [8192][4096] f32
        const float* __restrict__ A,     // [4096][128]  f32
        const float* __restrict__ B,     // [128][4096]  f32
        __bf16* __restrict__ At,         // ws [128][4096]
        __bf16* __restrict__ Bt,         // ws [4096][128]
        __bf16* __restrict__ Up,         // ws [2][8192][128]
        float* __restrict__ out) {       // [8192][4096] f32
    __shared__ __align__(16) char smem[49152];
    const int t    = threadIdx.x;
    const int b    = blockIdx.x;
    const int lane = t & 63;
    const int wid  = t >> 6;
    cg::grid_group grid = cg::this_grid();

    // ---------------- Phase 0: transpose+cast A and B ----------------
    {
        float (*tile)[33] = reinterpret_cast<float (*)[33]>(smem);
        const int tx = t & 31;
        const int ty31 = (t >> 5) & 7;      // use first 256 threads' pattern:
        // Only threads 0..255 participate (same as proven tcast2 at 256 thr).
        if (t < 256) {
            // A[4096][128] -> At[128][4096]
            const int bc = (b & 3) * 32;    // col in A
            const int br = (b >> 2) * 32;   // row in A
#pragma unroll
            for (int p = 0; p < 4; ++p)
                tile[ty31 + p * 8][tx] = A[(size_t)(br + ty31 + p * 8) * 128 + bc + tx];
        }
        __syncthreads();
        if (t < 256) {
            const int bc = (b & 3) * 32;
            const int br = (b >> 2) * 32;
#pragma unroll
            for (int p = 0; p < 4; ++p)
                At[(size_t)(bc + ty31 + p * 8) * 4096 + br + tx] =
                    (__bf16)tile[tx][ty31 + p * 8];
        }
        __syncthreads();
        if (t < 256) {
            // B[128][4096] -> Bt[4096][128]
            const int bc = (b & 127) * 32;  // col in B
            const int br = (b >> 7) * 32;   // row in B
#pragma unroll
            for (int p = 0; p < 4; ++p)
                tile[ty31 + p * 8][tx] = B[(size_t)(br + ty31 + p * 8) * 4096 + bc + tx];
        }
        __syncthreads();
        if (t < 256) {
            const int bc = (b & 127) * 32;
            const int br = (b >> 7) * 32;
#pragma unroll
            for (int p = 0; p < 4; ++p)
                Bt[(size_t)(bc + ty31 + p * 8) * 128 + br + tx] =
                    (__bf16)tile[tx][ty31 + p * 8];
        }
    }
    grid.sync();

    // ---------------- Phase A: gemm1b (proven), ksplit 2 ----------------
    {
        __bf16 (*sI)[32][64]  = reinterpret_cast<__bf16 (*)[32][64]>(smem);          // [2][32][64]
        __bf16 (*sA)[128][64] = reinterpret_cast<__bf16 (*)[128][64]>(smem + 8192);  // [2][128][64]
        const int mt    = b & 255;
        const int kz    = b >> 8;          // 0 / 1
        const int brow  = mt * 32;
        const int ktoff = kz * 32;
        __bf16* Uw = Up + (size_t)kz * 8192 * 128;
        const int wm = (wid >> 2) << 4;    // 0 / 16
        const int wn = (wid & 3) << 5;     // 0 / 32 / 64 / 96
        const int irow = t >> 4;           // 0..31
        const int icol = (t & 15) << 2;    // 0..60
        const int fr = lane & 15;
        const int fk = (lane >> 4) << 3;

        f32x4 acc[2] = {};
        f32x4 ireg;
        u32x4 areg[2];

        auto load_tile = [&](int kt) {
            const int kg = (ktoff + kt) * 64;
            ireg = *reinterpret_cast<const f32x4*>(
                &inp[(size_t)(brow + irow) * 4096 + kg + icol]);
#pragma unroll
            for (int p = 0; p < 2; ++p) {
                const int c = t + p * 512;
                const int row = c >> 3, col = (c & 7) << 3;
                areg[p] = *reinterpret_cast<const u32x4*>(
                    &At[(size_t)row * 4096 + kg + col]);
            }
        };
        auto store_tile = [&](int buf) {
            bf16x4 h = { (__bf16)ireg[0], (__bf16)ireg[1], (__bf16)ireg[2], (__bf16)ireg[3] };
            *reinterpret_cast<bf16x4*>(&sI[buf][irow][icol ^ ((irow & 7) << 3)]) = h;
#pragma unroll
            for (int p = 0; p < 2; ++p) {
                const int c = t + p * 512;
                const int row = c >> 3, col = (c & 7) << 3;
                *reinterpret_cast<u32x4*>(&sA[buf][row][col ^ ((row & 7) << 3)]) = areg[p];
            }
        };

        load_tile(0);
        store_tile(0);
        int cur = 0;
        for (int kt = 0; kt < 32; ++kt) {
            if (kt < 31) load_tile(kt + 1);
            __syncthreads();
#pragma unroll
            for (int ks = 0; ks < 2; ++ks) {
                const int k = ks * 32 + fk;
                const int ar = wm + fr;
                bf16x8 af = *reinterpret_cast<const bf16x8*>(
                    &sI[cur][ar][k ^ ((ar & 7) << 3)]);
#pragma unroll
                for (int n = 0; n < 2; ++n) {
                    const int nr = wn + n * 16 + fr;
                    bf16x8 bfv = *reinterpret_cast<const bf16x8*>(
                        &sA[cur][nr][k ^ ((nr & 7) << 3)]);
                    acc[n] = __builtin_amdgcn_mfma_f32_16x16x32_bf16(af, bfv, acc[n], 0, 0, 0);
                }
            }
            __syncthreads();
            if (kt < 31) store_tile(cur ^ 1);
            cur ^= 1;
        }

        const int orow = brow + wm + ((lane >> 4) << 2);
#pragma unroll
        for (int n = 0; n < 2; ++n)
#pragma unroll
            for (int v = 0; v < 4; ++v)
                Uw[(size_t)(orow + v) * 128 + wn + n * 16 + fr] = (__bf16)acc[n][v];
    }
    grid.sync();

    // ---------------- Phase B: reduce + gemm2 (8 col-tiles/block) --------
    {
        __bf16 (*sU)[128] = reinterpret_cast<__bf16 (*)[128]>(smem);           // [64][128]
        __bf16 (*sB)[128] = reinterpret_cast<__bf16 (*)[128]>(smem + 16384);   // [128][128]
        const int bs    = (b & 7) * 64 + (b >> 3);   // bijective XCD swizzle
        const int brow  = (bs >> 2) * 64;            // 128 row groups
        const int bcol0 = (bs & 3) * 1024;           // 4 col groups of 1024

        // stage U rows once, with merged Up0+Up1 reduce (f32 add -> bf16)
#pragma unroll
        for (int p = 0; p < 2; ++p) {
            const int c = t + p * 512;
            const int row = c >> 4, col = (c & 15) << 3;
            const size_t off = (size_t)(brow + row) * 128 + col;
            bf16x8 a = *reinterpret_cast<const bf16x8*>(Up + off);
            bf16x8 bb = *reinterpret_cast<const bf16x8*>(Up + (size_t)8192 * 128 + off);
            bf16x8 r;
#pragma unroll
            for (int e = 0; e < 8; ++e) r[e] = (__bf16)((float)a[e] + (float)bb[e]);
            *reinterpret_cast<bf16x8*>(&sU[row][col ^ ((row & 7) << 3)]) = r;
        }

        const int wm = (wid >> 2) << 5;   // 0 / 32
        const int wn = (wid & 3) << 5;    // 0 / 32 / 64 / 96
        const int fr = lane & 15;
        const int fk = (lane >> 4) << 3;
        const int g4 = (lane >> 4) << 2;

        for (int j = 0; j < 8; ++j) {
            const int bcol = bcol0 + j * 128;
            // stage Bt tile (128 n-rows x 128 k)
#pragma unroll
            for (int p = 0; p < 4; ++p) {
                const int c = t + p * 512;
                const int row = c >> 4, col = (c & 15) << 3;
                u32x4 v = *reinterpret_cast<const u32x4*>(
                    &Bt[(size_t)(bcol + row) * 128 + col]);
                *reinterpret_cast<u32x4*>(&sB[row][col ^ ((row & 7) << 3)]) = v;
            }
            __syncthreads();

            // swapped-operand accumulators (transposed C/D) — proven R6
            f32x4 acc_s[2][2] = {};
#pragma unroll
            for (int ks = 0; ks < 4; ++ks) {
                const int k = ks * 32 + fk;
                bf16x8 af[2], bfv[2];
#pragma unroll
                for (int am = 0; am < 2; ++am) {
                    const int r = wm + am * 16 + fr;
                    af[am] = *reinterpret_cast<const bf16x8*>(&sU[r][k ^ ((r & 7) << 3)]);
                }
#pragma unroll
                for (int bn = 0; bn < 2; ++bn) {
                    const int r = wn + bn * 16 + fr;
                    bfv[bn] = *reinterpret_cast<const bf16x8*>(&sB[r][k ^ ((r & 7) << 3)]);
                }
#pragma unroll
                for (int bn = 0; bn < 2; ++bn)
#pragma unroll
                    for (int am = 0; am < 2; ++am)
                        acc_s[bn][am] = __builtin_amdgcn_mfma_f32_16x16x32_bf16(
                            bfv[bn], af[am], acc_s[bn][am], 0, 0, 0);
            }

            // epilogue: dwordx4 stores
#pragma unroll
            for (int am = 0; am < 2; ++am) {
                const int orow = brow + wm + am * 16 + fr;
#pragma unroll
                for (int bn = 0; bn < 2; ++bn) {
                    const int ocol = bcol + wn + bn * 16 + g4;
                    *reinterpret_cast<f32x4*>(&out[(size_t)orow * 4096 + ocol]) = acc_s[bn][am];
                }
            }
            __syncthreads();   // sB reads done before next restage
        }
    }
}

// ===========================================================================
// Fallback path (proven R6 kernels) — used if cooperative occupancy < 2.
// ===========================================================================
__global__ void tcast2(const float* __restrict__ A, __bf16* __restrict__ At,
                       const float* __restrict__ B, __bf16* __restrict__ Bt) {
    __shared__ float tile[32][33];
    int b = blockIdx.x;
    const float* src;
    __bf16* dst;
    int R, C, bxi, byi;
    if (b < 512) { src = A; dst = At; R = 4096; C = 128;  bxi = b & 3;   byi = b >> 2; }
    else { b -= 512; src = B; dst = Bt; R = 128;  C = 4096; bxi = b & 127; byi = b >> 7; }
    const int bc = bxi * 32;
    const int br = byi * 32;
    const int tx = threadIdx.x & 31;
    const int ty = threadIdx.x >> 5;
#pragma unroll
    for (int p = 0; p < 4; ++p)
        tile[ty + p * 8][tx] = src[(size_t)(br + ty + p * 8) * C + bc + tx];
    __syncthreads();
#pragma unroll
    for (int p = 0; p < 4; ++p)
        dst[(size_t)(bc + ty + p * 8) * R + br + tx] = (__bf16)tile[tx][ty + p * 8];
}

__global__ __launch_bounds__(512, 1) void gemm1b(const float* __restrict__ inp,
                                                 const __bf16* __restrict__ At,
                                                 __bf16* __restrict__ Uout,
                                                 int ktiles) {
    __shared__ __align__(16) __bf16 sI[2][32][64];
    __shared__ __align__(16) __bf16 sA[2][128][64];
    const int t     = threadIdx.x;
    const int brow  = blockIdx.x * 32;
    const int ktoff = blockIdx.y * ktiles;
    __bf16* Up = Uout + (size_t)blockIdx.y * 8192 * 128;
    const int lane = t & 63;
    const int wid  = t >> 6;
    const int wm   = (wid >> 2) << 4;
    const int wn   = (wid & 3) << 5;
    const int irow = t >> 4;
    const int icol = (t & 15) << 2;
    const int fr = lane & 15;
    const int fk = (lane >> 4) << 3;

    f32x4 acc[2] = {};
    f32x4 ireg;
    u32x4 areg[2];

    auto load_tile = [&](int kt) {
        const int kg = (ktoff + kt) * 64;
        ireg = *reinterpret_cast<const f32x4*>(
            &inp[(size_t)(brow + irow) * 4096 + kg + icol]);
#pragma unroll
        for (int p = 0; p < 2; ++p) {
            const int c = t + p * 512;
            const int row = c >> 3, col = (c & 7) << 3;
            areg[p] = *reinterpret_cast<const u32x4*>(
                &At[(size_t)row * 4096 + kg + col]);
        }
    };
    auto store_tile = [&](int buf) {
        bf16x4 h = { (__bf16)ireg[0], (__bf16)ireg[1], (__bf16)ireg[2], (__bf16)ireg[3] };
        *reinterpret_cast<bf16x4*>(&sI[buf][irow][icol ^ ((irow & 7) << 3)]) = h;
#pragma unroll
        for (int p = 0; p < 2; ++p) {
            const int c = t + p * 512;
            const int row = c >> 3, col = (c & 7) << 3;
            *reinterpret_cast<u32x4*>(&sA[buf][row][col ^ ((row & 7) << 3)]) = areg[p];
        }
    };

    load_tile(0);
    store_tile(0);
    int cur = 0;
    for (int kt = 0; kt < ktiles; ++kt) {
        if (kt < ktiles - 1) load_tile(kt + 1);
        __syncthreads();
#pragma unroll
        for (int ks = 0; ks < 2; ++ks) {
            const int k = ks * 32 + fk;
            const int ar = wm + fr;
            bf16x8 af = *reinterpret_cast<const bf16x8*>(
                &sI[cur][ar][k ^ ((ar & 7) << 3)]);
#pragma unroll
            for (int n = 0; n < 2; ++n) {
                const int nr = wn + n * 16 + fr;
                bf16x8 bfv = *reinterpret_cast<const bf16x8*>(
                    &sA[cur][nr][k ^ ((nr & 7) << 3)]);
                acc[n] = __builtin_amdgcn_mfma_f32_16x16x32_bf16(af, bfv, acc[n], 0, 0, 0);
            }
        }
        __syncthreads();
        if (kt < ktiles - 1) store_tile(cur ^ 1);
        cur ^= 1;
    }

    const int orow = brow + wm + ((lane >> 4) << 2);
#pragma unroll
    for (int n = 0; n < 2; ++n)
#pragma unroll
        for (int v = 0; v < 4; ++v)
            Up[(size_t)(orow + v) * 128 + wn + n * 16 + fr] = (__bf16)acc[n][v];
}

__global__ void reduceU(const __bf16* __restrict__ Up, __bf16* __restrict__ U,
                        int ksplit) {
    const size_t i = ((size_t)blockIdx.x * 256 + threadIdx.x) * 8;
    float s[8] = {};
    for (int j = 0; j < ksplit; ++j) {
        bf16x8 a = *reinterpret_cast<const bf16x8*>(Up + (size_t)j * 8192 * 128 + i);
#pragma unroll
        for (int e = 0; e < 8; ++e) s[e] += (float)a[e];
    }
    bf16x8 r;
#pragma unroll
    for (int e = 0; e < 8; ++e) r[e] = (__bf16)s[e];
    *reinterpret_cast<bf16x8*>(U + i) = r;
}

__global__ __launch_bounds__(256, 1) void gemm2(const __bf16* __restrict__ U,
                                                const __bf16* __restrict__ Bt,
                                                float* __restrict__ out) {
    __shared__ __align__(16) __bf16 sU[64][128];
    __shared__ __align__(16) __bf16 sB[128][128];
    const int t    = threadIdx.x;
    const int lane = t & 63;
    const int wid  = t >> 6;
    const int bx0  = blockIdx.x;
    const int bx   = (bx0 & 7) * 512 + (bx0 >> 3);
    const int brow = (bx >> 5) * 64;
    const int bcol = (bx & 31) * 128;

#pragma unroll
    for (int p = 0; p < 4; ++p) {
        const int c = t + p * 256;
        const int row = c >> 4, col = (c & 15) << 3;
        u32x4 v = *reinterpret_cast<const u32x4*>(&U[(size_t)(brow + row) * 128 + col]);
        *reinterpret_cast<u32x4*>(&sU[row][col ^ ((row & 7) << 3)]) = v;
    }
#pragma unroll
    for (int p = 0; p < 8; ++p) {
        const int c = t + p * 256;
        const int row = c >> 4, col = (c & 15) << 3;
        u32x4 v = *reinterpret_cast<const u32x4*>(&Bt[(size_t)(bcol + row) * 128 + col]);
        *reinterpret_cast<u32x4*>(&sB[row][col ^ ((row & 7) << 3)]) = v;
    }
    __syncthreads();

    const int wm = (wid >> 1) << 5;
    const int wn = (wid & 1) << 6;
    const int fr = lane & 15;
    const int fk = (lane >> 4) << 3;

    f32x4 acc_s[4][2] = {};
#pragma unroll
    for (int ks = 0; ks < 4; ++ks) {
        const int k = ks * 32 + fk;
        bf16x8 af[2];
#pragma unroll
        for (int am = 0; am < 2; ++am) {
            const int r = wm + am * 16 + fr;
            af[am] = *reinterpret_cast<const bf16x8*>(&sU[r][k ^ ((r & 7) << 3)]);
        }
#pragma unroll
        for (int bn = 0; bn < 4; ++bn) {
            const int r = wn + bn * 16 + fr;
            bf16x8 bfv = *reinterpret_cast<const bf16x8*>(&sB[r][k ^ ((r & 7) << 3)]);
#pragma unroll
            for (int am = 0; am < 2; ++am)
                acc_s[bn][am] = __builtin_amdgcn_mfma_f32_16x16x32_bf16(
                    bfv, af[am], acc_s[bn][am], 0, 0, 0);
        }
    }

    const int g4 = (lane >> 4) << 2;
#pragma unroll
    for (int am = 0; am < 2; ++am) {
        const int orow = brow + wm + am * 16 + fr;
#pragma unroll
        for (int bn = 0; bn < 4; ++bn) {
            const int ocol = bcol + wn + bn * 16 + g4;
            *reinterpret_cast<f32x4*>(&out[(size_t)orow * 4096 + ocol]) = acc_s[bn][am];
        }
    }
}

// ---------------------------------------------------------------------------
extern "C" void kernel_launch(void* const* d_in, const int* in_sizes, int n_in,
                              void* d_out, int out_size, void* d_ws, size_t ws_size,
                              hipStream_t stream) {
    const float* inp = (const float*)d_in[0];   // [8192,4096]
    const float* A   = (const float*)d_in[1];   // [4096,128]
    const float* B   = (const float*)d_in[2];   // [128,4096]
    float* out = (float*)d_out;                 // [8192,4096]

    char* ws = (char*)d_ws;
    __bf16* At = (__bf16*)(ws);                 // [128][4096]     1 MB
    __bf16* Bt = (__bf16*)(ws + (1 << 20));     // [4096][128]     1 MB
    __bf16* Up = (__bf16*)(ws + (2 << 20));     // [2][8192][128]  4 MB
    __bf16* U  = (__bf16*)(ws + (6 << 20));     // [8192][128]     2 MB (fallback)

    int nb = 0;
    hipError_t qe = hipOccupancyMaxActiveBlocksPerMultiprocessor(&nb, fused_all, 512, 0);
    const bool coop = (qe == hipSuccess) && (nb >= 2) && (ws_size >= (size_t)(8 << 20));

    if (coop) {
        void* args[] = { (void*)&inp, (void*)&A, (void*)&B,
                         (void*)&At, (void*)&Bt, (void*)&Up, (void*)&out };
        hipLaunchCooperativeKernel((const void*)fused_all, dim3(512), dim3(512),
                                   args, 0, stream);
    } else {
        tcast2<<<1024, 256, 0, stream>>>(A, At, B, Bt);
        if (ws_size >= (size_t)(8 << 20)) {
            gemm1b<<<dim3(256, 2), 512, 0, stream>>>(inp, At, Up, 32);
            reduceU<<<512, 256, 0, stream>>>(Up, U, 2);
        } else {
            U = Up;  // reuse as single buffer
            gemm1b<<<dim3(256, 1), 512, 0, stream>>>(inp, At, U, 64);
        }
        gemm2<<<4096, 256, 0, stream>>>(U, Bt, out);
    }
}